// Round 2
// baseline (473.473 us; speedup 1.0000x reference)
//
#include <hip/hip_runtime.h>

// Problem: xs (T=32768, 1, D=2048) fp32.
//   ys    = xs + 1                (T*D fp32, first in d_out)
//   carry = sum_t (xs[t]+1)       (D fp32, appended after ys in d_out)
// Pure streaming: 256 MB read + 256 MB write -> HBM-bound, ~81 us ideal.

constexpr int T = 32768;
constexpr int D = 2048;
constexpr int D4 = D / 4;                    // 512 float4 per row
constexpr int BLOCK = 256;                   // threads per block
constexpr int NBLOCKS = 1024;                // 4 blocks/CU on 256 CUs
constexpr int ROWS_PER_BLOCK = T / NBLOCKS;  // 32

__global__ __launch_bounds__(BLOCK)
void BiasAndSum_kernel(const float4* __restrict__ x,
                       float4* __restrict__ ys,
                       float* __restrict__ carry)
{
    const int t = threadIdx.x;                       // 0..255
    // Thread t owns float4 columns t and t+256 of every row in the strip.
    const long base = (long)blockIdx.x * ROWS_PER_BLOCK * D4;

    float4 acc0 = make_float4(0.f, 0.f, 0.f, 0.f);
    float4 acc1 = make_float4(0.f, 0.f, 0.f, 0.f);

    #pragma unroll 4
    for (int r = 0; r < ROWS_PER_BLOCK; ++r) {
        const long idx = base + (long)r * D4 + t;
        float4 v0 = x[idx];
        float4 v1 = x[idx + 256];

        v0.x += 1.f; v0.y += 1.f; v0.z += 1.f; v0.w += 1.f;
        v1.x += 1.f; v1.y += 1.f; v1.z += 1.f; v1.w += 1.f;

        ys[idx]       = v0;
        ys[idx + 256] = v1;

        acc0.x += v0.x; acc0.y += v0.y; acc0.z += v0.z; acc0.w += v0.w;
        acc1.x += v1.x; acc1.y += v1.y; acc1.z += v1.z; acc1.w += v1.w;
    }

    // carry is zeroed by hipMemsetAsync before this kernel; device-scope atomics.
    float* c0 = carry + 4 * t;          // columns 4t..4t+3
    atomicAdd(c0 + 0, acc0.x);
    atomicAdd(c0 + 1, acc0.y);
    atomicAdd(c0 + 2, acc0.z);
    atomicAdd(c0 + 3, acc0.w);
    float* c1 = carry + 1024 + 4 * t;   // columns 1024+4t..1024+4t+3
    atomicAdd(c1 + 0, acc1.x);
    atomicAdd(c1 + 1, acc1.y);
    atomicAdd(c1 + 2, acc1.z);
    atomicAdd(c1 + 3, acc1.w);
}

extern "C" void kernel_launch(void* const* d_in, const int* in_sizes, int n_in,
                              void* d_out, int out_size, void* d_ws, size_t ws_size,
                              hipStream_t stream) {
    const float* x = (const float*)d_in[0];
    float* out = (float*)d_out;
    float* ys = out;                       // T*D elements
    float* carry = out + (size_t)T * D;    // D elements

    // Harness re-poisons d_out to 0xAA before every timed launch: zero the
    // carry tail (8 KB) so the atomic accumulation starts clean.
    hipMemsetAsync(carry, 0, D * sizeof(float), stream);

    BiasAndSum_kernel<<<NBLOCKS, BLOCK, 0, stream>>>(
        (const float4*)x, (float4*)ys, carry);
}